// Round 13
// baseline (1102.366 us; speedup 1.0000x reference)
//
#include <hip/hip_runtime.h>

#define HID  64
#define SEQT 1024
#define NB   4

typedef _Float16 h8 __attribute__((ext_vector_type(8)));
typedef float    f4 __attribute__((ext_vector_type(4)));

__device__ __forceinline__ float rcpf(float x){ return __builtin_amdgcn_rcpf(x); }
__device__ __forceinline__ float sigm(float x){ return rcpf(1.0f + __expf(-x)); }
__device__ __forceinline__ float tanh_fast(float x){
    // 1 - 2/(e^{2x}+1); correct saturation at +-inf
    return 1.0f - 2.0f * rcpf(__expf(2.0f * x) + 1.0f);
}

#define MFMA16(A,B,C) __builtin_amdgcn_mfma_f32_16x16x32_f16((A),(B),(C),0,0,0)

// split fp32 -> f16 hi + f16 lo (exact residual; 3-term product ~2^-24 rel)
__device__ __forceinline__ void split8(const float* __restrict__ p, h8& hi, h8& lo) {
    float4 u = *(const float4*)p;
    float4 v = *(const float4*)(p + 4);
    float vv[8] = {u.x, u.y, u.z, u.w, v.x, v.y, v.z, v.w};
    #pragma unroll
    for (int e = 0; e < 8; ++e) {
        _Float16 h = (_Float16)vv[e];
        hi[e] = h;
        lo[e] = (_Float16)(vv[e] - (float)h);
    }
}

// v12 with the W-rows PERMUTED so each lane's D-fragment holds all 4 gate
// types of ONE unit: wave m's A-row rho loads W row 64*(rho&3) + 4m + (rho>>2).
// With D mapping (col=lane&15=batch, row=4*(lane>>4)+reg), lane (g4,r16) gets
// acc[r] = gate-type-r preact of unit u=4m+g4, batch r16 -> the LSTM cell runs
// directly on MFMA accumulators. G0/G1 LDS round-trip and one barrier are
// GONE: iter = {ds_read h -> L0 chain(6) -> L1 chain(12) -> cell0 -> cell1 ->
// ds_write h -> ONE barrier}. Cell VALU/trans overlaps other waves' MFMA
// (m114). Lanes r16>=4 compute replica cells (cols 4-15 are batch replicas,
// consistent by construction) and don't write.
// 16 waves (4/SIMD), wave m owns units 4m..4m+3 of BOTH pipelined layers
// (L0 step t, L1 step t-1). Double-buffered h; read/write buffers disjoint
// by parity, so ONE end-of-iter barrier is race-free.
__global__ __launch_bounds__(1024, 4)
void lstm2_v13(const float* __restrict__ x,
               const float* __restrict__ W_ih0, const float* __restrict__ W_hh0,
               const float* __restrict__ b_ih0, const float* __restrict__ b_hh0,
               const float* __restrict__ W_ih1, const float* __restrict__ W_hh1,
               const float* __restrict__ b_ih1, const float* __restrict__ b_hh1,
               const float* __restrict__ fc1_w, const float* __restrict__ fc1_b,
               const float* __restrict__ fc2_w, const float* __restrict__ fc2_b,
               float* __restrict__ out, int nblk)
{
    const int blk = blockIdx.x;
    if (blk >= nblk) return;
    const int tid = threadIdx.x;
    const int w   = tid >> 6;          // wave 0..15: owns units 4w..4w+3
    const int l   = tid & 63;          // lane
    const int r16 = l & 15;            // A row in tile / D col (batch)
    const int g4  = l >> 4;            // k-subgroup / D row group
    const int cc  = r16 & 3;           // batch col (cols replicated x4)
    const int u   = 4 * w + g4;        // unit this lane's cell handles
    const int B0  = blk * NB;

    // ---------------- LDS: h state (double-buffered) + final h2 ------------
    __shared__ __align__(16) _Float16 h1h[2][NB][80], h1l[2][NB][80];
    __shared__ __align__(16) _Float16 h2h[2][NB][80], h2l[2][NB][80];
    __shared__ __align__(16) float h2f[NB][64];

    // ---------------- A-fragments, ROW-PERMUTED, hi/lo f16 ------------------
    // A-row r16 <- W row 64*(r16&3) + 4w + (r16>>2)
    h8 a0[2][2];   // [ks][hi/lo]  W_hh0
    h8 a1[4][2];   // ks 0,1: W_ih1 ; ks 2,3: W_hh1
    {
        const int rowP = 64 * (r16 & 3) + 4 * w + (r16 >> 2);
        #pragma unroll
        for (int ks = 0; ks < 2; ++ks) {
            split8(W_hh0 + rowP * HID + ks * 32 + g4 * 8, a0[ks][0],     a0[ks][1]);
            split8(W_ih1 + rowP * HID + ks * 32 + g4 * 8, a1[ks][0],     a1[ks][1]);
            split8(W_hh1 + rowP * HID + ks * 32 + g4 * 8, a1[2 + ks][0], a1[2 + ks][1]);
        }
    }

    // ---------------- cell constants: gate r of unit u ----------------------
    float bias0v[4], bias1v[4], wih0v[4];
    #pragma unroll
    for (int r = 0; r < 4; ++r) {
        const int grow = 64 * r + u;
        bias0v[r] = b_ih0[grow] + b_hh0[grow];
        bias1v[r] = b_ih1[grow] + b_hh1[grow];
        wih0v[r]  = W_ih0[grow];
    }

    // ---------------- init ----------------
    if (tid < 320) {   // 320 ints = 2*NB*80 halves per array
        ((int*)h1h)[tid] = 0; ((int*)h1l)[tid] = 0;
        ((int*)h2h)[tid] = 0; ((int*)h2l)[tid] = 0;
    }
    // x chunk: lane 4d+b holds x[batch b][t+d]; 16 steps per window
    const size_t xbase = (size_t)(B0 + (l & 3)) * SEQT;
    float xc  = x[xbase + (l >> 2)];
    float xcn = 0.0f;
    float c1 = 0.0f, c2 = 0.0f;
    __syncthreads();

    const f4 z4 = {0.f, 0.f, 0.f, 0.f};

    // one pipelined iteration; RB/WB compile-time at every call site
    auto step = [&](int t_, int RB1, int RB2, int WB1, int WB2,
                    bool L0A, bool L1A, bool FIN) {
        if (((t_ & 15) == 0) && (t_ + 16 < SEQT))
            xcn = x[xbase + t_ + 16 + (l >> 2)];

        // ---- B-fragments up front ----
        h8 b1h0 = *(const h8*)&h1h[RB1][cc][g4 * 8];
        h8 b1h1 = *(const h8*)&h1h[RB1][cc][32 + g4 * 8];
        h8 b1l0 = *(const h8*)&h1l[RB1][cc][g4 * 8];
        h8 b1l1 = *(const h8*)&h1l[RB1][cc][32 + g4 * 8];
        h8 b2h0, b2h1, b2l0, b2l1;
        if (L1A) {
            b2h0 = *(const h8*)&h2h[RB2][cc][g4 * 8];
            b2h1 = *(const h8*)&h2h[RB2][cc][32 + g4 * 8];
            b2l0 = *(const h8*)&h2l[RB2][cc][g4 * 8];
            b2l1 = *(const h8*)&h2l[RB2][cc][32 + g4 * 8];
        }

        f4 e, p;
        __builtin_amdgcn_s_setprio(1);
        if (L0A) {   // G0(t) = Whh0 * h1(t-1): one C-chain, depth 6
            e = MFMA16(a0[0][0], b1h0, z4);
            e = MFMA16(a0[0][1], b1h0, e);
            e = MFMA16(a0[0][0], b1l0, e);
            e = MFMA16(a0[1][0], b1h1, e);
            e = MFMA16(a0[1][1], b1h1, e);
            e = MFMA16(a0[1][0], b1l1, e);
        }
        if (L1A) {   // G1(t-1) = Wih1*h1(t-1) + Whh1*h2(t-2): one C-chain, 12
            p = MFMA16(a1[0][0], b1h0, z4);
            p = MFMA16(a1[0][1], b1h0, p);
            p = MFMA16(a1[0][0], b1l0, p);
            p = MFMA16(a1[1][0], b1h1, p);
            p = MFMA16(a1[1][1], b1h1, p);
            p = MFMA16(a1[1][0], b1l1, p);
            p = MFMA16(a1[2][0], b2h0, p);
            p = MFMA16(a1[2][1], b2h0, p);
            p = MFMA16(a1[2][0], b2l0, p);
            p = MFMA16(a1[3][0], b2h1, p);
            p = MFMA16(a1[3][1], b2h1, p);
            p = MFMA16(a1[3][0], b2l1, p);
        }
        __builtin_amdgcn_s_setprio(0);

        // ---- cell0 on acc e: unit u, batch cc (lanes r16>=4 are replicas) --
        if (L0A) {
            const float xt = __shfl(xc, ((t_ & 15) << 2) | cc);
            float pi = e[0] + fmaf(xt, wih0v[0], bias0v[0]);
            float pf = e[1] + fmaf(xt, wih0v[1], bias0v[1]);
            float pg = e[2] + fmaf(xt, wih0v[2], bias0v[2]);
            float po = e[3] + fmaf(xt, wih0v[3], bias0v[3]);
            float iv = sigm(pi), fv = sigm(pf);
            float gv = tanh_fast(pg), ov = sigm(po);
            c1 = fmaf(fv, c1, iv * gv);
            float hv = ov * tanh_fast(c1);
            _Float16 hh = (_Float16)hv;
            if (r16 < NB) {
                h1h[WB1][r16][u] = hh;
                h1l[WB1][r16][u] = (_Float16)(hv - (float)hh);
            }
        }
        // ---- cell1 on acc p ----
        if (L1A) {
            float pi = p[0] + bias1v[0];
            float pf = p[1] + bias1v[1];
            float pg = p[2] + bias1v[2];
            float po = p[3] + bias1v[3];
            float iv = sigm(pi), fv = sigm(pf);
            float gv = tanh_fast(pg), ov = sigm(po);
            c2 = fmaf(fv, c2, iv * gv);
            float hv = ov * tanh_fast(c2);
            _Float16 hh = (_Float16)hv;
            if (r16 < NB) {
                h2h[WB2][r16][u] = hh;
                h2l[WB2][r16][u] = (_Float16)(hv - (float)hh);
                if (FIN) h2f[r16][u] = hv;
            }
        }
        if ((t_ & 15) == 15) xc = xcn;
        __syncthreads();                       // h1(t), h2(t-1) visible
    };

    step(0, 1, 0, 0, 1, true,  false, false);
    step(1, 0, 1, 1, 0, true,  true,  false);
    #pragma unroll 1
    for (int t = 2; t < SEQT; t += 2) {
        step(t,     1, 0, 0, 1, true, true, false);
        step(t + 1, 0, 1, 1, 0, true, true, false);
    }
    step(SEQT, 1, 0, 0, 1, false, true, true);

    // ---------------- FC head: wave w (<4) -> batch w ----------------
    if (w < 4) {
        float z = 0.0f;
        if (l < 32) {
            float acc = fc1_b[l];
            const f4* hvp = (const f4*)h2f[w];
            const f4* wvp = (const f4*)(fc1_w + l * HID);
            #pragma unroll
            for (int q = 0; q < 16; ++q) {
                f4 hq = hvp[q], wk = wvp[q];
                acc = fmaf(hq[0], wk[0], acc); acc = fmaf(hq[1], wk[1], acc);
                acc = fmaf(hq[2], wk[2], acc); acc = fmaf(hq[3], wk[3], acc);
            }
            z = fmaxf(acc, 0.0f) * fc2_w[l];
        }
        #pragma unroll
        for (int off = 32; off > 0; off >>= 1) z += __shfl_xor(z, off);
        if (l == 0) out[B0 + w] = z + fc2_b[0];
    }
}

extern "C" void kernel_launch(void* const* d_in, const int* in_sizes, int n_in,
                              void* d_out, int out_size, void* d_ws, size_t ws_size,
                              hipStream_t stream) {
    const float* x     = (const float*)d_in[0];
    const float* W_ih0 = (const float*)d_in[1];
    const float* W_hh0 = (const float*)d_in[2];
    const float* b_ih0 = (const float*)d_in[3];
    const float* b_hh0 = (const float*)d_in[4];
    const float* W_ih1 = (const float*)d_in[5];
    const float* W_hh1 = (const float*)d_in[6];
    const float* b_ih1 = (const float*)d_in[7];
    const float* b_hh1 = (const float*)d_in[8];
    const float* fc1_w = (const float*)d_in[9];
    const float* fc1_b = (const float*)d_in[10];
    const float* fc2_w = (const float*)d_in[11];
    const float* fc2_b = (const float*)d_in[12];
    float* out = (float*)d_out;

    const int batch = in_sizes[0] / SEQT;   // 1024
    const int nblk  = batch / NB;           // 256 blocks, 1 per CU
    dim3 grid(nblk), block(1024);
    hipLaunchKernelGGL(lstm2_v13, grid, block, 0, stream,
                       x, W_ih0, W_hh0, b_ih0, b_hh0,
                       W_ih1, W_hh1, b_ih1, b_hh1,
                       fc1_w, fc1_b, fc2_w, fc2_b, out, nblk);
}

// Round 14
// 778.619 us; speedup vs baseline: 1.4158x; 1.4158x over previous
//
#include <hip/hip_runtime.h>

#define HID  64
#define SEQT 1024
#define NB   4

typedef _Float16 h8 __attribute__((ext_vector_type(8)));
typedef float    f4 __attribute__((ext_vector_type(4)));
typedef float    v2f __attribute__((ext_vector_type(2)));

__device__ __forceinline__ float rcpf(float x){ return __builtin_amdgcn_rcpf(x); }
__device__ __forceinline__ float sigm(float x){ return rcpf(1.0f + __expf(-x)); }
__device__ __forceinline__ float tanh_fast(float x){
    // 1 - 2/(e^{2x}+1); correct saturation at +-inf
    return 1.0f - 2.0f * rcpf(__expf(2.0f * x) + 1.0f);
}
__device__ __forceinline__ v2f pkfma(v2f a, v2f b, v2f c){
    return __builtin_elementwise_fma(a, b, c);      // -> v_pk_fma_f32
}

#define MFMA16(A,B,C) __builtin_amdgcn_mfma_f32_16x16x32_f16((A),(B),(C),0,0,0)

// split fp32 -> f16 hi + f16 lo (exact residual)
__device__ __forceinline__ void split8(const float* __restrict__ p, h8& hi, h8& lo) {
    float4 u = *(const float4*)p;
    float4 v = *(const float4*)(p + 4);
    float vv[8] = {u.x, u.y, u.z, u.w, v.x, v.y, v.z, v.w};
    #pragma unroll
    for (int e = 0; e < 8; ++e) {
        _Float16 h = (_Float16)vv[e];
        hi[e] = h;
        lo[e] = (_Float16)(vv[e] - (float)h);
    }
}

// v12 structure with 2-TERM precision: the hidden state h is rounded to f16
// in the cell and used EXACTLY (h_lo == 0). Then w.h = w_hi.h + w_lo.h is
// exact given the (f16-valued) state -> MFMA per wave drops 18 -> 12
// (floor 1397 -> 931 cy/SIMD/iter), ds_reads halve, cell drops the lo split.
// Numerics: recurrence runs on f16-rounded h (rel 5e-4 state perturbation,
// contractive through gates); gate preacts exact given state; fp32 accum.
// Everything else is v12 verbatim: 1024 thr = 16 waves (4/SIMD), wave m owns
// M-tile m of both pipelined layers (L0 step t: chain of 4; L1 step t-1:
// chain of 8); G0/G1 via LDS; cell0 waves 0-3, cell1 waves 4-7; 2 barriers;
// peeled x2 unroll (compile-time buffer indices); x prefetch; setprio.
__global__ __launch_bounds__(1024, 4)
void lstm2_v14(const float* __restrict__ x,
               const float* __restrict__ W_ih0, const float* __restrict__ W_hh0,
               const float* __restrict__ b_ih0, const float* __restrict__ b_hh0,
               const float* __restrict__ W_ih1, const float* __restrict__ W_hh1,
               const float* __restrict__ b_ih1, const float* __restrict__ b_hh1,
               const float* __restrict__ fc1_w, const float* __restrict__ fc1_b,
               const float* __restrict__ fc2_w, const float* __restrict__ fc2_b,
               float* __restrict__ out, int nblk)
{
    const int blk = blockIdx.x;
    if (blk >= nblk) return;
    const int tid = threadIdx.x;
    const int w   = tid >> 6;          // wave 0..15 = M-tile index
    const int l   = tid & 63;          // lane
    const int r16 = l & 15;            // A row in tile / D col (batch)
    const int g4  = l >> 4;            // k-subgroup / D row group
    const int cc  = r16 & 3;           // batch col for B-frag broadcast
    const int cb  = w & 3;             // cell batch (waves 0-7)
    const int B0  = blk * NB;

    // ---------------- LDS ----------------
    __shared__ __align__(16) _Float16 h1f[2][NB][80];   // f16-exact h1
    __shared__ __align__(16) _Float16 h2f16[2][NB][80]; // f16-exact h2
    __shared__ __align__(16) float G0[NB][260];
    __shared__ __align__(16) float G1[NB][260];
    __shared__ __align__(16) float h2fin[NB][64];

    // ---------------- A-fragments: ONE tile (rows 16w+r16), hi/lo ----------
    h8 a0[2][2];   // [ks][hi/lo]  W_hh0
    h8 a1[4][2];   // ks 0,1: W_ih1 ; ks 2,3: W_hh1
    {
        const int row = 16 * w + r16;
        #pragma unroll
        for (int ks = 0; ks < 2; ++ks) {
            split8(W_hh0 + row * HID + ks * 32 + g4 * 8, a0[ks][0],     a0[ks][1]);
            split8(W_ih1 + row * HID + ks * 32 + g4 * 8, a1[ks][0],     a1[ks][1]);
            split8(W_hh1 + row * HID + ks * 32 + g4 * 8, a1[2 + ks][0], a1[2 + ks][1]);
        }
    }

    // ---------------- cell constants, packed v2f (waves 0-7) ----------------
    const float* bip = (w < 4) ? b_ih0 : b_ih1;
    const float* bhp = (w < 4) ? b_hh0 : b_hh1;
    v2f biasA, biasB, wihA, wihB;
    biasA.x = bip[l]       + bhp[l];
    biasA.y = bip[l + 64]  + bhp[l + 64];
    biasB.x = bip[l + 128] + bhp[l + 128];
    biasB.y = bip[l + 192] + bhp[l + 192];
    if (w < 4) {
        wihA.x = W_ih0[l];       wihA.y = W_ih0[l + 64];
        wihB.x = W_ih0[l + 128]; wihB.y = W_ih0[l + 192];
    } else {
        wihA = (v2f){0.f, 0.f};  wihB = (v2f){0.f, 0.f};
    }

    // ---------------- init ----------------
    if (tid < 320) {   // 320 ints = 2*NB*80 halves per array
        ((int*)h1f)[tid] = 0; ((int*)h2f16)[tid] = 0;
    }
    const size_t xbase = (size_t)(B0 + cb) * SEQT;
    float xc = 0.0f, xcn = 0.0f;
    if (w < 4) xc = x[xbase + l];      // chunk for t = 0..63 (lane = t offset)
    float cst = 0.0f;                  // c1 (waves 0-3) / c2 (waves 4-7)
    __syncthreads();

    const f4 z4 = {0.f, 0.f, 0.f, 0.f};

    // one pipelined iteration; RB/WB compile-time at every call site
    auto step = [&](int t_, int RB1, int RB2, int WB1, int WB2,
                    bool L0A, bool L1A, bool FIN) {
        if (w < 4 && ((t_ & 63) == 0) && (t_ + 64 < SEQT))
            xcn = x[xbase + t_ + 64 + l];

        // ---- phase-1 B-frags: h1(t-1), f16-exact (hi only) ----
        h8 b1h0 = *(const h8*)&h1f[RB1][cc][g4 * 8];
        h8 b1h1 = *(const h8*)&h1f[RB1][cc][32 + g4 * 8];

        __builtin_amdgcn_s_setprio(1);
        if (L0A) {   // G0(t) = Whh0 * h1(t-1): one C-chain, depth 4
            f4 e = MFMA16(a0[0][0], b1h0, z4);
            e = MFMA16(a0[0][1], b1h0, e);
            e = MFMA16(a0[1][0], b1h1, e);
            e = MFMA16(a0[1][1], b1h1, e);
            if (r16 < NB)
                *(f4*)&G0[r16][16 * w + 4 * g4] = e;
        }
        if (L1A) {   // G1(t-1) = Wih1*h1(t-1) + Whh1*h2(t-2): one C-chain, 8
            h8 b2h0 = *(const h8*)&h2f16[RB2][cc][g4 * 8];
            h8 b2h1 = *(const h8*)&h2f16[RB2][cc][32 + g4 * 8];
            f4 p = MFMA16(a1[0][0], b1h0, z4);
            p = MFMA16(a1[0][1], b1h0, p);
            p = MFMA16(a1[1][0], b1h1, p);
            p = MFMA16(a1[1][1], b1h1, p);
            p = MFMA16(a1[2][0], b2h0, p);
            p = MFMA16(a1[2][1], b2h0, p);
            p = MFMA16(a1[3][0], b2h1, p);
            p = MFMA16(a1[3][1], b2h1, p);
            if (r16 < NB)
                *(f4*)&G1[r16][16 * w + 4 * g4] = p;
        }
        __builtin_amdgcn_s_setprio(0);
        __syncthreads();                       // G0(t), G1(t-1) ready

        // ---- cell: waves 0-3 cell0(batch w); waves 4-7 cell1(batch w-4) ----
        if (w < 4) {
            if (L0A) {
                const float xt = __shfl(xc, t_ & 63);
                v2f xt2 = {xt, xt};
                v2f gA = {G0[w][l],       G0[w][l + 64]};
                v2f gB = {G0[w][l + 128], G0[w][l + 192]};
                v2f pA = gA + pkfma(xt2, wihA, biasA);
                v2f pB = gB + pkfma(xt2, wihB, biasB);
                float iv = sigm(pA.x), fv = sigm(pA.y);
                float gv = tanh_fast(pB.x), ov = sigm(pB.y);
                cst = fmaf(fv, cst, iv * gv);
                float hv = ov * tanh_fast(cst);
                h1f[WB1][w][l] = (_Float16)hv;     // f16-exact state
            }
        } else if (w < 8) {
            if (L1A) {
                v2f gA = {G1[cb][l],       G1[cb][l + 64]};
                v2f gB = {G1[cb][l + 128], G1[cb][l + 192]};
                v2f pA = gA + biasA;
                v2f pB = gB + biasB;
                float iv = sigm(pA.x), fv = sigm(pA.y);
                float gv = tanh_fast(pB.x), ov = sigm(pB.y);
                cst = fmaf(fv, cst, iv * gv);
                float hv = ov * tanh_fast(cst);
                _Float16 hh = (_Float16)hv;
                h2f16[WB2][cb][l] = hh;            // f16-exact state
                if (FIN) h2fin[cb][l] = (float)hh;
            }
        }
        if ((t_ & 63) == 63) xc = xcn;
        __syncthreads();                       // h1(t), h2(t-1) visible
    };

    step(0, 1, 0, 0, 1, true,  false, false);
    step(1, 0, 1, 1, 0, true,  true,  false);
    #pragma unroll 1
    for (int t = 2; t < SEQT; t += 2) {
        step(t,     1, 0, 0, 1, true, true, false);
        step(t + 1, 0, 1, 1, 0, true, true, false);
    }
    step(SEQT, 1, 0, 0, 1, false, true, true);

    // ---------------- FC head: wave w (<4) -> batch w ----------------
    if (w < 4) {
        float z = 0.0f;
        if (l < 32) {
            float acc = fc1_b[l];
            const f4* hvp = (const f4*)h2fin[w];
            const f4* wvp = (const f4*)(fc1_w + l * HID);
            #pragma unroll
            for (int q = 0; q < 16; ++q) {
                f4 hq = hvp[q], wk = wvp[q];
                acc = fmaf(hq[0], wk[0], acc); acc = fmaf(hq[1], wk[1], acc);
                acc = fmaf(hq[2], wk[2], acc); acc = fmaf(hq[3], wk[3], acc);
            }
            z = fmaxf(acc, 0.0f) * fc2_w[l];
        }
        #pragma unroll
        for (int off = 32; off > 0; off >>= 1) z += __shfl_xor(z, off);
        if (l == 0) out[B0 + w] = z + fc2_b[0];
    }
}

extern "C" void kernel_launch(void* const* d_in, const int* in_sizes, int n_in,
                              void* d_out, int out_size, void* d_ws, size_t ws_size,
                              hipStream_t stream) {
    const float* x     = (const float*)d_in[0];
    const float* W_ih0 = (const float*)d_in[1];
    const float* W_hh0 = (const float*)d_in[2];
    const float* b_ih0 = (const float*)d_in[3];
    const float* b_hh0 = (const float*)d_in[4];
    const float* W_ih1 = (const float*)d_in[5];
    const float* W_hh1 = (const float*)d_in[6];
    const float* b_ih1 = (const float*)d_in[7];
    const float* b_hh1 = (const float*)d_in[8];
    const float* fc1_w = (const float*)d_in[9];
    const float* fc1_b = (const float*)d_in[10];
    const float* fc2_w = (const float*)d_in[11];
    const float* fc2_b = (const float*)d_in[12];
    float* out = (float*)d_out;

    const int batch = in_sizes[0] / SEQT;   // 1024
    const int nblk  = batch / NB;           // 256 blocks, 1 per CU
    dim3 grid(nblk), block(1024);
    hipLaunchKernelGGL(lstm2_v14, grid, block, 0, stream,
                       x, W_ih0, W_hh0, b_ih0, b_hh0,
                       W_ih1, W_hh1, b_ih1, b_hh1,
                       fc1_w, fc1_b, fc2_w, fc2_b, out, nblk);
}

// Round 15
// 678.245 us; speedup vs baseline: 1.6253x; 1.1480x over previous
//
#include <hip/hip_runtime.h>

#define HID  64
#define SEQT 1024
#define NB   4

typedef _Float16 h8 __attribute__((ext_vector_type(8)));
typedef float    f4 __attribute__((ext_vector_type(4)));
typedef float    v2f __attribute__((ext_vector_type(2)));

__device__ __forceinline__ float rcpf(float x){ return __builtin_amdgcn_rcpf(x); }
__device__ __forceinline__ float sigm(float x){ return rcpf(1.0f + __expf(-x)); }
__device__ __forceinline__ float tanh_fast(float x){
    // 1 - 2/(e^{2x}+1); correct saturation at +-inf
    return 1.0f - 2.0f * rcpf(__expf(2.0f * x) + 1.0f);
}
__device__ __forceinline__ v2f pkfma(v2f a, v2f b, v2f c){
    return __builtin_elementwise_fma(a, b, c);      // -> v_pk_fma_f32
}

#define MFMA16(A,B,C) __builtin_amdgcn_mfma_f32_16x16x32_f16((A),(B),(C),0,0,0)

// split fp32 -> f16 hi + f16 lo (exact residual)
__device__ __forceinline__ void split8(const float* __restrict__ p, h8& hi, h8& lo) {
    float4 u = *(const float4*)p;
    float4 v = *(const float4*)(p + 4);
    float vv[8] = {u.x, u.y, u.z, u.w, v.x, v.y, v.z, v.w};
    #pragma unroll
    for (int e = 0; e < 8; ++e) {
        _Float16 h = (_Float16)vv[e];
        hi[e] = h;
        lo[e] = (_Float16)(vv[e] - (float)h);
    }
}

// v14 (2-term, f16-exact state) with PHASE-INTERLEAVED schedule: no phase is
// cell-only, so the cell's quarter-rate trans chain runs under other waves'
// MFMA instead of in dedicated dead time.
//   Phase A (iter t): G0(t) MFMA on ALL 16 waves  ||  cell1(t-2) on waves 4-7
//   barrier
//   Phase B (iter t): G1(t-1) MFMA on ALL 16 waves ||  cell0(t) on waves 0-3
//   barrier
// Deps (all barrier-ordered): G0(t)<-h1(t-1)[B(t-1)]; G1(t-1)<-h1(t-1) +
// h2(t-2)[A(t)]; cell1(t-2)<-G1(t-2)[B(t-1)]; cell0(t)<-G0(t)[A(t)].
// G0/G1 single-buffered (write->read separated by exactly one barrier);
// h1/h2 parity double-buffered: h1(t)->buf t&1 (write B(t)), h2(t-2)->buf t&1
// (write A(t)). b1 frags are read once in Phase A and live across the barrier
// (their buffer is not written until B(t+1)). Cell G-reads issue before the
// wave's own MFMA cluster so LDS latency hides under MFMA issue.
__global__ __launch_bounds__(1024, 4)
void lstm2_v15(const float* __restrict__ x,
               const float* __restrict__ W_ih0, const float* __restrict__ W_hh0,
               const float* __restrict__ b_ih0, const float* __restrict__ b_hh0,
               const float* __restrict__ W_ih1, const float* __restrict__ W_hh1,
               const float* __restrict__ b_ih1, const float* __restrict__ b_hh1,
               const float* __restrict__ fc1_w, const float* __restrict__ fc1_b,
               const float* __restrict__ fc2_w, const float* __restrict__ fc2_b,
               float* __restrict__ out, int nblk)
{
    const int blk = blockIdx.x;
    if (blk >= nblk) return;
    const int tid = threadIdx.x;
    const int w   = tid >> 6;          // wave 0..15 = M-tile index
    const int l   = tid & 63;          // lane
    const int r16 = l & 15;            // A row in tile / D col (batch)
    const int g4  = l >> 4;            // k-subgroup / D row group
    const int cc  = r16 & 3;           // batch col for B-frag broadcast
    const int cb  = w & 3;             // cell batch (waves 0-7)
    const int B0  = blk * NB;

    // ---------------- LDS ----------------
    __shared__ __align__(16) _Float16 h1f[2][NB][80];   // f16-exact h1
    __shared__ __align__(16) _Float16 h2f16[2][NB][80]; // f16-exact h2
    __shared__ __align__(16) float G0[NB][260];
    __shared__ __align__(16) float G1[NB][260];
    __shared__ __align__(16) float h2fin[NB][64];

    // ---------------- A-fragments: ONE tile (rows 16w+r16), hi/lo ----------
    h8 a0[2][2];   // [ks][hi/lo]  W_hh0
    h8 a1[4][2];   // ks 0,1: W_ih1 ; ks 2,3: W_hh1
    {
        const int row = 16 * w + r16;
        #pragma unroll
        for (int ks = 0; ks < 2; ++ks) {
            split8(W_hh0 + row * HID + ks * 32 + g4 * 8, a0[ks][0],     a0[ks][1]);
            split8(W_ih1 + row * HID + ks * 32 + g4 * 8, a1[ks][0],     a1[ks][1]);
            split8(W_hh1 + row * HID + ks * 32 + g4 * 8, a1[2 + ks][0], a1[2 + ks][1]);
        }
    }

    // ---------------- cell constants, packed v2f (waves 0-7) ----------------
    const float* bip = (w < 4) ? b_ih0 : b_ih1;
    const float* bhp = (w < 4) ? b_hh0 : b_hh1;
    v2f biasA, biasB, wihA, wihB;
    biasA.x = bip[l]       + bhp[l];
    biasA.y = bip[l + 64]  + bhp[l + 64];
    biasB.x = bip[l + 128] + bhp[l + 128];
    biasB.y = bip[l + 192] + bhp[l + 192];
    if (w < 4) {
        wihA.x = W_ih0[l];       wihA.y = W_ih0[l + 64];
        wihB.x = W_ih0[l + 128]; wihB.y = W_ih0[l + 192];
    } else {
        wihA = (v2f){0.f, 0.f};  wihB = (v2f){0.f, 0.f};
    }

    // ---------------- init ----------------
    if (tid < 320) {   // 320 ints = 2*NB*80 halves per array
        ((int*)h1f)[tid] = 0; ((int*)h2f16)[tid] = 0;
    }
    const size_t xbase = (size_t)(B0 + cb) * SEQT;
    float xc = 0.0f, xcn = 0.0f;
    if (w < 4) xc = x[xbase + l];      // chunk for t = 0..63 (lane = t offset)
    float cst = 0.0f;                  // c1 (waves 0-3) / c2 (waves 4-7)
    __syncthreads();

    const f4 z4 = {0.f, 0.f, 0.f, 0.f};
    const bool meC0 = (w < 4);
    const bool meC1 = (w >= 4 && w < 8);

    // one interleaved iteration; P = t&1 compile-time at every call site
    auto step = [&](int t_, int P,
                    bool L0A, bool G1A, bool C0A, bool C1A, bool FIN) {
        const int RB1 = P ^ 1;         // buf of h1(t-1)

        // ================= Phase A: G0(t) MFMA || cell1(t-2) =================
        if (meC0 && ((t_ & 63) == 0) && (t_ + 64 < SEQT))
            xcn = x[xbase + t_ + 64 + l];

        // b1 frags: live across the barrier into Phase B (buf untouched there)
        h8 b1h0, b1h1;
        if (L0A || G1A) {
            b1h0 = *(const h8*)&h1f[RB1][cc][g4 * 8];
            b1h1 = *(const h8*)&h1f[RB1][cc][32 + g4 * 8];
        }
        // cell1's G-reads issue before the MFMA cluster (latency hides under it)
        v2f gA1, gB1;
        if (C1A && meC1) {
            gA1 = (v2f){G1[cb][l],       G1[cb][l + 64]};
            gB1 = (v2f){G1[cb][l + 128], G1[cb][l + 192]};
        }
        __builtin_amdgcn_s_setprio(1);
        if (L0A) {   // G0(t) = Whh0 * h1(t-1): one C-chain, depth 4
            f4 e = MFMA16(a0[0][0], b1h0, z4);
            e = MFMA16(a0[0][1], b1h0, e);
            e = MFMA16(a0[1][0], b1h1, e);
            e = MFMA16(a0[1][1], b1h1, e);
            if (r16 < NB)
                *(f4*)&G0[r16][16 * w + 4 * g4] = e;
        }
        __builtin_amdgcn_s_setprio(0);
        if (C1A && meC1) {             // cell1(t-2), batch cb
            v2f pA = gA1 + biasA;
            v2f pB = gB1 + biasB;
            float iv = sigm(pA.x), fv = sigm(pA.y);
            float gv = tanh_fast(pB.x), ov = sigm(pB.y);
            cst = fmaf(fv, cst, iv * gv);
            float hv = ov * tanh_fast(cst);
            _Float16 hh = (_Float16)hv;
            h2f16[P][cb][l] = hh;      // h2(t-2) -> buf (t-2)&1 == P
            if (FIN) h2fin[cb][l] = (float)hh;
        }
        __syncthreads();               // G0(t), h2(t-2) visible

        // ================= Phase B: G1(t-1) MFMA || cell0(t) =================
        v2f gA0, gB0;
        if (C0A && meC0) {
            gA0 = (v2f){G0[w][l],       G0[w][l + 64]};
            gB0 = (v2f){G0[w][l + 128], G0[w][l + 192]};
        }
        __builtin_amdgcn_s_setprio(1);
        if (G1A) {   // G1(t-1) = Wih1*h1(t-1) + Whh1*h2(t-2): one C-chain, 8
            h8 b2h0 = *(const h8*)&h2f16[P][cc][g4 * 8];
            h8 b2h1 = *(const h8*)&h2f16[P][cc][32 + g4 * 8];
            f4 p = MFMA16(a1[0][0], b1h0, z4);
            p = MFMA16(a1[0][1], b1h0, p);
            p = MFMA16(a1[1][0], b1h1, p);
            p = MFMA16(a1[1][1], b1h1, p);
            p = MFMA16(a1[2][0], b2h0, p);
            p = MFMA16(a1[2][1], b2h0, p);
            p = MFMA16(a1[3][0], b2h1, p);
            p = MFMA16(a1[3][1], b2h1, p);
            if (r16 < NB)
                *(f4*)&G1[r16][16 * w + 4 * g4] = p;
        }
        __builtin_amdgcn_s_setprio(0);
        if (C0A && meC0) {             // cell0(t), batch w
            const float xt = __shfl(xc, t_ & 63);
            v2f xt2 = {xt, xt};
            v2f pA = gA0 + pkfma(xt2, wihA, biasA);
            v2f pB = gB0 + pkfma(xt2, wihB, biasB);
            float iv = sigm(pA.x), fv = sigm(pA.y);
            float gv = tanh_fast(pB.x), ov = sigm(pB.y);
            cst = fmaf(fv, cst, iv * gv);
            float hv = ov * tanh_fast(cst);
            h1f[P][w][l] = (_Float16)hv;   // h1(t) -> buf t&1 == P
        }
        if ((t_ & 63) == 63) xc = xcn;
        __syncthreads();               // G1(t-1), h1(t) visible
    };

    //            t    P  L0A    G1A    C0A    C1A    FIN
    step(        0,    0, true,  false, true,  false, false);
    step(        1,    1, true,  true,  true,  false, false);
    #pragma unroll 1
    for (int t = 2; t < SEQT; t += 2) {
        step(t,      0, true,  true,  true,  true,  false);
        step(t + 1,  1, true,  true,  true,  true,  false);
    }
    step(     SEQT,    0, false, true,  false, true,  false);
    step( SEQT + 1,    1, false, false, false, true,  true );

    // ---------------- FC head: wave w (<4) -> batch w ----------------
    if (w < 4) {
        float z = 0.0f;
        if (l < 32) {
            float acc = fc1_b[l];
            const f4* hvp = (const f4*)h2fin[w];
            const f4* wvp = (const f4*)(fc1_w + l * HID);
            #pragma unroll
            for (int q = 0; q < 16; ++q) {
                f4 hq = hvp[q], wk = wvp[q];
                acc = fmaf(hq[0], wk[0], acc); acc = fmaf(hq[1], wk[1], acc);
                acc = fmaf(hq[2], wk[2], acc); acc = fmaf(hq[3], wk[3], acc);
            }
            z = fmaxf(acc, 0.0f) * fc2_w[l];
        }
        #pragma unroll
        for (int off = 32; off > 0; off >>= 1) z += __shfl_xor(z, off);
        if (l == 0) out[B0 + w] = z + fc2_b[0];
    }
}

extern "C" void kernel_launch(void* const* d_in, const int* in_sizes, int n_in,
                              void* d_out, int out_size, void* d_ws, size_t ws_size,
                              hipStream_t stream) {
    const float* x     = (const float*)d_in[0];
    const float* W_ih0 = (const float*)d_in[1];
    const float* W_hh0 = (const float*)d_in[2];
    const float* b_ih0 = (const float*)d_in[3];
    const float* b_hh0 = (const float*)d_in[4];
    const float* W_ih1 = (const float*)d_in[5];
    const float* W_hh1 = (const float*)d_in[6];
    const float* b_ih1 = (const float*)d_in[7];
    const float* b_hh1 = (const float*)d_in[8];
    const float* fc1_w = (const float*)d_in[9];
    const float* fc1_b = (const float*)d_in[10];
    const float* fc2_w = (const float*)d_in[11];
    const float* fc2_b = (const float*)d_in[12];
    float* out = (float*)d_out;

    const int batch = in_sizes[0] / SEQT;   // 1024
    const int nblk  = batch / NB;           // 256 blocks, 1 per CU
    dim3 grid(nblk), block(1024);
    hipLaunchKernelGGL(lstm2_v15, grid, block, 0, stream,
                       x, W_ih0, W_hh0, b_ih0, b_hh0,
                       W_ih1, W_hh1, b_ih1, b_hh1,
                       fc1_w, fc1_b, fc2_w, fc2_b, out, nblk);
}

// Round 16
// 590.170 us; speedup vs baseline: 1.8679x; 1.1492x over previous
//
#include <hip/hip_runtime.h>

#define HID  64
#define SEQT 1024
#define NB   4

typedef _Float16 h8 __attribute__((ext_vector_type(8)));
typedef float    f4 __attribute__((ext_vector_type(4)));
typedef float    v2f __attribute__((ext_vector_type(2)));

__device__ __forceinline__ float rcpf(float x){ return __builtin_amdgcn_rcpf(x); }
__device__ __forceinline__ float sigm(float x){ return rcpf(1.0f + __expf(-x)); }
__device__ __forceinline__ float tanh_fast(float x){
    // 1 - 2/(e^{2x}+1); correct saturation at +-inf
    return 1.0f - 2.0f * rcpf(__expf(2.0f * x) + 1.0f);
}
__device__ __forceinline__ v2f pkfma(v2f a, v2f b, v2f c){
    return __builtin_elementwise_fma(a, b, c);      // -> v_pk_fma_f32
}

#define MFMA16(A,B,C) __builtin_amdgcn_mfma_f32_16x16x32_f16((A),(B),(C),0,0,0)

// round 8 fp32 values to f16 (1-term weights)
__device__ __forceinline__ h8 cvt8(const float* __restrict__ p) {
    float4 u = *(const float4*)p;
    float4 v = *(const float4*)(p + 4);
    h8 r;
    r[0] = (_Float16)u.x; r[1] = (_Float16)u.y;
    r[2] = (_Float16)u.z; r[3] = (_Float16)u.w;
    r[4] = (_Float16)v.x; r[5] = (_Float16)v.y;
    r[6] = (_Float16)v.z; r[7] = (_Float16)v.w;
    return r;
}

// v15 schedule with 1-TERM f16 weights (w_lo dropped): L0 = 2 MFMA/wave,
// L1 = 4 MFMA/wave -> 24 MFMA/SIMD/iter, floor 931 -> 466 cy.
// Accuracy basis: round-14 measured that the h-f16 quantization (~2.4e-4/step
// perturbation) yields total absmax 1.22e-4 -> recurrence is contractive.
// Weight rounding adds ~3.6e-5/step (7x smaller) -> predicted absmax well
// under the 5.98e-4 threshold. h state stays f16-exact; biases fp32 exact.
// Schedule (phase-interleaved, v15-proven):
//   Phase A: G0(t) MFMA all 16 waves || cell1(t-2) waves 4-7; barrier
//   Phase B: G1(t-1) MFMA all 16 waves || cell0(t) waves 0-3; barrier
// 1024 thr = 16 waves (4/SIMD), NB=4 batches/block, 256 blocks (1/CU) —
// the provably machine-filling partition. G single-buffered, h parity
// double-buffered, peeled x2 unroll, x prefetch, setprio on MFMA clusters.
__global__ __launch_bounds__(1024, 4)
void lstm2_v16(const float* __restrict__ x,
               const float* __restrict__ W_ih0, const float* __restrict__ W_hh0,
               const float* __restrict__ b_ih0, const float* __restrict__ b_hh0,
               const float* __restrict__ W_ih1, const float* __restrict__ W_hh1,
               const float* __restrict__ b_ih1, const float* __restrict__ b_hh1,
               const float* __restrict__ fc1_w, const float* __restrict__ fc1_b,
               const float* __restrict__ fc2_w, const float* __restrict__ fc2_b,
               float* __restrict__ out, int nblk)
{
    const int blk = blockIdx.x;
    if (blk >= nblk) return;
    const int tid = threadIdx.x;
    const int w   = tid >> 6;          // wave 0..15 = M-tile index
    const int l   = tid & 63;          // lane
    const int r16 = l & 15;            // A row in tile / D col (batch)
    const int g4  = l >> 4;            // k-subgroup / D row group
    const int cc  = r16 & 3;           // batch col for B-frag broadcast
    const int cb  = w & 3;             // cell batch (waves 0-7)
    const int B0  = blk * NB;

    // ---------------- LDS ----------------
    __shared__ __align__(16) _Float16 h1f[2][NB][80];   // f16-exact h1
    __shared__ __align__(16) _Float16 h2f16[2][NB][80]; // f16-exact h2
    __shared__ __align__(16) float G0[NB][260];
    __shared__ __align__(16) float G1[NB][260];
    __shared__ __align__(16) float h2fin[NB][64];

    // ---------------- A-fragments: ONE tile (rows 16w+r16), f16 1-term ------
    h8 a0[2];   // [ks]  W_hh0
    h8 a1[4];   // ks 0,1: W_ih1 ; ks 2,3: W_hh1
    {
        const int row = 16 * w + r16;
        #pragma unroll
        for (int ks = 0; ks < 2; ++ks) {
            a0[ks]     = cvt8(W_hh0 + row * HID + ks * 32 + g4 * 8);
            a1[ks]     = cvt8(W_ih1 + row * HID + ks * 32 + g4 * 8);
            a1[2 + ks] = cvt8(W_hh1 + row * HID + ks * 32 + g4 * 8);
        }
    }

    // ---------------- cell constants, packed v2f (waves 0-7) ----------------
    const float* bip = (w < 4) ? b_ih0 : b_ih1;
    const float* bhp = (w < 4) ? b_hh0 : b_hh1;
    v2f biasA, biasB, wihA, wihB;
    biasA.x = bip[l]       + bhp[l];
    biasA.y = bip[l + 64]  + bhp[l + 64];
    biasB.x = bip[l + 128] + bhp[l + 128];
    biasB.y = bip[l + 192] + bhp[l + 192];
    if (w < 4) {
        wihA.x = W_ih0[l];       wihA.y = W_ih0[l + 64];
        wihB.x = W_ih0[l + 128]; wihB.y = W_ih0[l + 192];
    } else {
        wihA = (v2f){0.f, 0.f};  wihB = (v2f){0.f, 0.f};
    }

    // ---------------- init ----------------
    if (tid < 320) {   // 320 ints = 2*NB*80 halves per array
        ((int*)h1f)[tid] = 0; ((int*)h2f16)[tid] = 0;
    }
    const size_t xbase = (size_t)(B0 + cb) * SEQT;
    float xc = 0.0f, xcn = 0.0f;
    if (w < 4) xc = x[xbase + l];      // chunk for t = 0..63 (lane = t offset)
    float cst = 0.0f;                  // c1 (waves 0-3) / c2 (waves 4-7)
    __syncthreads();

    const f4 z4 = {0.f, 0.f, 0.f, 0.f};
    const bool meC0 = (w < 4);
    const bool meC1 = (w >= 4 && w < 8);

    // one interleaved iteration; P = t&1 compile-time at every call site
    auto step = [&](int t_, int P,
                    bool L0A, bool G1A, bool C0A, bool C1A, bool FIN) {
        const int RB1 = P ^ 1;         // buf of h1(t-1)

        // ================= Phase A: G0(t) MFMA || cell1(t-2) =================
        if (meC0 && ((t_ & 63) == 0) && (t_ + 64 < SEQT))
            xcn = x[xbase + t_ + 64 + l];

        // b1 frags: live across the barrier into Phase B (buf untouched there)
        h8 b1h0, b1h1;
        if (L0A || G1A) {
            b1h0 = *(const h8*)&h1f[RB1][cc][g4 * 8];
            b1h1 = *(const h8*)&h1f[RB1][cc][32 + g4 * 8];
        }
        // cell1's G-reads issue before the MFMA cluster (latency hides under it)
        v2f gA1, gB1;
        if (C1A && meC1) {
            gA1 = (v2f){G1[cb][l],       G1[cb][l + 64]};
            gB1 = (v2f){G1[cb][l + 128], G1[cb][l + 192]};
        }
        __builtin_amdgcn_s_setprio(1);
        if (L0A) {   // G0(t) = Whh0 * h1(t-1): one C-chain, depth 2
            f4 e = MFMA16(a0[0], b1h0, z4);
            e = MFMA16(a0[1], b1h1, e);
            if (r16 < NB)
                *(f4*)&G0[r16][16 * w + 4 * g4] = e;
        }
        __builtin_amdgcn_s_setprio(0);
        if (C1A && meC1) {             // cell1(t-2), batch cb
            v2f pA = gA1 + biasA;
            v2f pB = gB1 + biasB;
            float iv = sigm(pA.x), fv = sigm(pA.y);
            float gv = tanh_fast(pB.x), ov = sigm(pB.y);
            cst = fmaf(fv, cst, iv * gv);
            float hv = ov * tanh_fast(cst);
            _Float16 hh = (_Float16)hv;
            h2f16[P][cb][l] = hh;      // h2(t-2) -> buf (t-2)&1 == P
            if (FIN) h2fin[cb][l] = (float)hh;
        }
        __syncthreads();               // G0(t), h2(t-2) visible

        // ================= Phase B: G1(t-1) MFMA || cell0(t) =================
        v2f gA0, gB0;
        if (C0A && meC0) {
            gA0 = (v2f){G0[w][l],       G0[w][l + 64]};
            gB0 = (v2f){G0[w][l + 128], G0[w][l + 192]};
        }
        __builtin_amdgcn_s_setprio(1);
        if (G1A) {   // G1(t-1) = Wih1*h1(t-1) + Whh1*h2(t-2): one C-chain, 4
            h8 b2h0 = *(const h8*)&h2f16[P][cc][g4 * 8];
            h8 b2h1 = *(const h8*)&h2f16[P][cc][32 + g4 * 8];
            f4 p = MFMA16(a1[0], b1h0, z4);
            p = MFMA16(a1[1], b1h1, p);
            p = MFMA16(a1[2], b2h0, p);
            p = MFMA16(a1[3], b2h1, p);
            if (r16 < NB)
                *(f4*)&G1[r16][16 * w + 4 * g4] = p;
        }
        __builtin_amdgcn_s_setprio(0);
        if (C0A && meC0) {             // cell0(t), batch w
            const float xt = __shfl(xc, t_ & 63);
            v2f xt2 = {xt, xt};
            v2f pA = gA0 + pkfma(xt2, wihA, biasA);
            v2f pB = gB0 + pkfma(xt2, wihB, biasB);
            float iv = sigm(pA.x), fv = sigm(pA.y);
            float gv = tanh_fast(pB.x), ov = sigm(pB.y);
            cst = fmaf(fv, cst, iv * gv);
            float hv = ov * tanh_fast(cst);
            h1f[P][w][l] = (_Float16)hv;   // h1(t) -> buf t&1 == P
        }
        if ((t_ & 63) == 63) xc = xcn;
        __syncthreads();               // G1(t-1), h1(t) visible
    };

    //            t    P  L0A    G1A    C0A    C1A    FIN
    step(        0,    0, true,  false, true,  false, false);
    step(        1,    1, true,  true,  true,  false, false);
    #pragma unroll 1
    for (int t = 2; t < SEQT; t += 2) {
        step(t,      0, true,  true,  true,  true,  false);
        step(t + 1,  1, true,  true,  true,  true,  false);
    }
    step(     SEQT,    0, false, true,  false, true,  false);
    step( SEQT + 1,    1, false, false, false, true,  true );

    // ---------------- FC head: wave w (<4) -> batch w ----------------
    if (w < 4) {
        float z = 0.0f;
        if (l < 32) {
            float acc = fc1_b[l];
            const f4* hvp = (const f4*)h2fin[w];
            const f4* wvp = (const f4*)(fc1_w + l * HID);
            #pragma unroll
            for (int q = 0; q < 16; ++q) {
                f4 hq = hvp[q], wk = wvp[q];
                acc = fmaf(hq[0], wk[0], acc); acc = fmaf(hq[1], wk[1], acc);
                acc = fmaf(hq[2], wk[2], acc); acc = fmaf(hq[3], wk[3], acc);
            }
            z = fmaxf(acc, 0.0f) * fc2_w[l];
        }
        #pragma unroll
        for (int off = 32; off > 0; off >>= 1) z += __shfl_xor(z, off);
        if (l == 0) out[B0 + w] = z + fc2_b[0];
    }
}

extern "C" void kernel_launch(void* const* d_in, const int* in_sizes, int n_in,
                              void* d_out, int out_size, void* d_ws, size_t ws_size,
                              hipStream_t stream) {
    const float* x     = (const float*)d_in[0];
    const float* W_ih0 = (const float*)d_in[1];
    const float* W_hh0 = (const float*)d_in[2];
    const float* b_ih0 = (const float*)d_in[3];
    const float* b_hh0 = (const float*)d_in[4];
    const float* W_ih1 = (const float*)d_in[5];
    const float* W_hh1 = (const float*)d_in[6];
    const float* b_ih1 = (const float*)d_in[7];
    const float* b_hh1 = (const float*)d_in[8];
    const float* fc1_w = (const float*)d_in[9];
    const float* fc1_b = (const float*)d_in[10];
    const float* fc2_w = (const float*)d_in[11];
    const float* fc2_b = (const float*)d_in[12];
    float* out = (float*)d_out;

    const int batch = in_sizes[0] / SEQT;   // 1024
    const int nblk  = batch / NB;           // 256 blocks, 1 per CU
    dim3 grid(nblk), block(1024);
    hipLaunchKernelGGL(lstm2_v16, grid, block, 0, stream,
                       x, W_ih0, W_hh0, b_ih0, b_hh0,
                       W_ih1, W_hh1, b_ih1, b_hh1,
                       fc1_w, fc1_b, fc2_w, fc2_b, out, nblk);
}